// Round 20
// baseline (73.328 us; speedup 1.0000x reference)
//
#include <hip/hip_runtime.h>
#include <math.h>

#define B 512
#define N 256
#define E 1024
#define D 256
#define H 256
#define C 8
#define U 64

typedef __fp16 h2 __attribute__((ext_vector_type(2)));
union UF { float f; h2 h; unsigned u; };

__device__ __forceinline__ float bc_f(h2 h) { UF u; u.h = h; return u.f; }
__device__ __forceinline__ h2 bc_h(float f) { UF u; u.f = f; return u.h; }

#if __has_builtin(__builtin_amdgcn_cvt_pkrtz)
__device__ __forceinline__ h2 pkh(float a, float b) { return __builtin_amdgcn_cvt_pkrtz(a, b); }
#else
__device__ __forceinline__ h2 pkh(float a, float b) { h2 r; r.x = (__fp16)a; r.y = (__fp16)b; return r; }
#endif

#if __has_builtin(__builtin_amdgcn_fdot2)
__device__ __forceinline__ float FDOT2(h2 a, h2 b, float c) { return __builtin_amdgcn_fdot2(a, b, c, false); }
#else
__device__ __forceinline__ float FDOT2(h2 a, h2 b, float c) {
    return fmaf((float)a.x, (float)b.x, fmaf((float)a.y, (float)b.y, c));
}
#endif

// ---------------------------------------------------------------------------
__device__ __forceinline__ float mask_val(const void* m, long i, int flag) {
    if (flag == 1) return ((const unsigned char*)m)[i] ? 1.f : 0.f;
    if (flag == 2) return (((const float*)m)[i] != 0.f) ? 1.f : 0.f;
    return ((const int*)m)[i] ? 1.f : 0.f;
}

// ---------------------------------------------------------------------------
// k_h1: A = relu(feat @ Wc1 + bc1), j-split x4. grid 512 (128 row-groups x
// 4 col-quarters), 256 thr (wave = row, 64 cols). 64KB weight slice/block.
// Also zeroes node_delta/out2/gate_part and sniffs mask dtype (block 0).
// ---------------------------------------------------------------------------
__global__ __launch_bounds__(256) void k_h1(
    const float* __restrict__ feat,
    const float* __restrict__ Wc1, const float* __restrict__ bc1,
    const unsigned int* __restrict__ amask_words,
    float* __restrict__ A_ws, int* __restrict__ flag,
    float* __restrict__ node_delta, float* __restrict__ out2,
    float* __restrict__ gate_part)
{
    __shared__ __align__(16) float sF[4][256];
    __shared__ int cls0, cls1;
    int t = threadIdx.x;
    int rg = blockIdx.x >> 2, jq = blockIdx.x & 3;
    int b0 = rg * 4;
    int r = t >> 6, lane = t & 63;
    int c = jq * 64 + lane;

    // zero partial buffers: 512 blocks x 256 thr
    {
        int idx = blockIdx.x * 256 + t;
        node_delta[idx] = 0.f;                                 // B*N = 131072
        ((float4*)out2)[idx] = make_float4(0.f, 0.f, 0.f, 0.f); // B*E/4 = 131072
        if (blockIdx.x < 8) gate_part[blockIdx.x * 256 + t] = 0.f; // 4*B
    }

    if (blockIdx.x == 0) {
        if (t == 0) { cls0 = 0; cls1 = 0; }
        __syncthreads();
        unsigned int wd = amask_words[t];
        if (wd != 0u && wd != 1u) {
            if (wd == 0x3f800000u) atomicOr(&cls1, 1);
            else                   atomicOr(&cls0, 1);
        }
        __syncthreads();
        if (t == 0) *flag = cls0 ? 1 : (cls1 ? 2 : 0);
    }

    #pragma unroll
    for (int rr = 0; rr < 4; rr++) sF[rr][t] = feat[(long)(b0 + rr) * D + t];
    __syncthreads();

    float a0 = bc1[c], a1 = 0.f;
    const float* Wp = Wc1 + c;
    for (int k0 = 0; k0 < D; k0 += 8) {
        float wv[8];
        #pragma unroll
        for (int i = 0; i < 8; i++) wv[i] = Wp[(long)(k0 + i) * H];
        #pragma unroll
        for (int i = 0; i < 8; i++) {
            float f = sF[r][k0 + i];
            if (i & 1) a1 = fmaf(f, wv[i], a1);
            else       a0 = fmaf(f, wv[i], a0);
        }
    }
    A_ws[(long)(b0 + r) * H + c] = fmaxf(a0 + a1, 0.f);
}

// ---------------------------------------------------------------------------
// k_h2: h = relu(A @ Wc2 + bc2), same shape as k_h1. Also writes per-jq gate
// partials to FIXED slots (summed in fixed order in k_h3 -> deterministic).
// ---------------------------------------------------------------------------
__global__ __launch_bounds__(256) void k_h2(
    const float* __restrict__ A_ws,
    const float* __restrict__ Wc2, const float* __restrict__ bc2,
    const float* __restrict__ Wg,
    float* __restrict__ h_ws, float* __restrict__ gate_part)
{
    __shared__ __align__(16) float sA[4][256];
    int t = threadIdx.x;
    int rg = blockIdx.x >> 2, jq = blockIdx.x & 3;
    int b0 = rg * 4;
    int r = t >> 6, lane = t & 63;
    int c = jq * 64 + lane;

    #pragma unroll
    for (int rr = 0; rr < 4; rr++) sA[rr][t] = A_ws[(long)(b0 + rr) * H + t];
    __syncthreads();

    float a0 = bc2[c], a1 = 0.f;
    const float* Wp = Wc2 + c;
    for (int k0 = 0; k0 < H; k0 += 8) {
        float wv[8];
        #pragma unroll
        for (int i = 0; i < 8; i++) wv[i] = Wp[(long)(k0 + i) * H];
        #pragma unroll
        for (int i = 0; i < 8; i++) {
            float f = sA[r][k0 + i];
            if (i & 1) a1 = fmaf(f, wv[i], a1);
            else       a0 = fmaf(f, wv[i], a0);
        }
    }
    float h = fmaxf(a0 + a1, 0.f);
    h_ws[(long)(b0 + r) * H + c] = h;

    // gate partial over this wave's 64 cols
    float p = h * Wg[c];
    #pragma unroll
    for (int m = 1; m < 64; m <<= 1) p += __shfl_xor(p, m);
    if (lane == 0) gate_part[(long)(b0 + r) * 4 + jq] = p;
}

// ---------------------------------------------------------------------------
// k_h3: base_n / base_e = h @ {Wn1,We1}[:256] + bias, j-split x4 x 2 mats.
// grid 1024. Block (mat=bid>>9, rg, jq). Also finalizes the gate (mat==0,
// jq==0 blocks; fixed-order partial sum -> deterministic threshold).
// ---------------------------------------------------------------------------
__global__ __launch_bounds__(256) void k_h3(
    const float* __restrict__ h_ws,
    const float* __restrict__ Wn1, const float* __restrict__ bn1,
    const float* __restrict__ We1, const float* __restrict__ be1,
    const float* __restrict__ bg,
    const float* __restrict__ margin, const float* __restrict__ brisk,
    const float* __restrict__ gate_part,
    float* __restrict__ base_n, float* __restrict__ base_e,
    float* __restrict__ out_gate)
{
    __shared__ __align__(16) float sH[4][256];
    int t = threadIdx.x;
    int bid = blockIdx.x;
    int mat = bid >> 9;
    int rem = bid & 511;
    int rg = rem >> 2, jq = rem & 3;
    int b0 = rg * 4;
    int r = t >> 6, lane = t & 63;
    int c = jq * 64 + lane;

    #pragma unroll
    for (int rr = 0; rr < 4; rr++) sH[rr][t] = h_ws[(long)(b0 + rr) * H + t];
    __syncthreads();

    const float* W3  = mat ? We1 : Wn1;
    float bias       = mat ? be1[c] : bn1[c];
    float* dst       = mat ? base_e : base_n;

    float a0 = bias, a1 = 0.f;
    const float* Wp = W3 + c;
    for (int k0 = 0; k0 < H; k0 += 8) {
        float wv[8];
        #pragma unroll
        for (int i = 0; i < 8; i++) wv[i] = Wp[(long)(k0 + i) * H];
        #pragma unroll
        for (int i = 0; i < 8; i++) {
            float f = sH[r][k0 + i];
            if (i & 1) a1 = fmaf(f, wv[i], a1);
            else       a0 = fmaf(f, wv[i], a0);
        }
    }
    dst[(long)(b0 + r) * H + c] = a0 + a1;

    if (mat == 0 && jq == 0 && t < 4) {
        int b = b0 + t;
        float s = ((gate_part[(long)b * 4 + 0] + gate_part[(long)b * 4 + 1])
                 + gate_part[(long)b * 4 + 2]) + gate_part[(long)b * 4 + 3];
        float lg = 1.f / (1.f + expf(-(s + bg[0])));
        out_gate[b] = ((margin[b] < 0.2f) || (brisk[b] > 0.6f) || (lg > 0.5f)) ? 1.f : 0.f;
    }
}

// ---------------------------------------------------------------------------
// k_ne: j-split x4 (64 j per block) — grid 2560, R14/R19 verbatim (cleaned).
// ---------------------------------------------------------------------------
__global__ __launch_bounds__(256, 2) void k_ne(
    const float* __restrict__ cs, const float* __restrict__ coords,
    const float* __restrict__ unc, const int* __restrict__ actions,
    const float* __restrict__ Wn1, const float* __restrict__ Wn2,
    const float* __restrict__ base_n,
    const float* __restrict__ es, const int* __restrict__ edges,
    const float* __restrict__ We1, const float* __restrict__ We2,
    const float* __restrict__ base_e,
    const float* __restrict__ gate,
    float* __restrict__ node_delta, float* __restrict__ out2)
{
    __shared__ __align__(16) float smem[3840];   // 15 KB
    int t = threadIdx.x;
    int w = t >> 6, lane = t & 63;

    if (blockIdx.x < 512) {
        // ================= NODE: 4 rows (wave=row), quarter j =============
        int rg = blockIdx.x >> 2;
        int jq = blockIdx.x & 3;
        int b0 = rg * 4;
        float* pack = smem;            // [64][12]
        float* sB   = smem + 768;      // [4][64]

        {
            int i = t;
            #pragma unroll
            for (int s = 0; s < 3; s++, i += 256) {
                int j = i / 12, k = i - j * 12;
                int jj = jq * 64 + j;
                float v;
                if (k < 10)       v = Wn1[(long)(H + k) * H + jj];
                else if (k == 10) v = Wn2[jj];
                else              v = 0.f;
                pack[i] = v;
            }
            int r = t >> 6, j = t & 63;
            sB[r * 64 + j] = base_n[(long)(b0 + r) * H + jq * 64 + j];
        }
        __syncthreads();

        int b = b0 + w;
        float g = gate[b];
        if (g != 0.f) {
            float f8v[4], ug[4], acc[4];
            float f0[4], f1[4], f2[4], f3[4], f4[4], f5[4], f6[4], f7[4];
            #pragma unroll
            for (int q = 0; q < 4; q++) {
                int n = q * 64 + lane;
                const float4* cp = (const float4*)(coords + ((long)b * N + n) * C);
                float4 c0 = cp[0], c1 = cp[1];
                f0[q] = c0.x; f1[q] = c0.y; f2[q] = c0.z; f3[q] = c0.w;
                f4[q] = c1.x; f5[q] = c1.y; f6[q] = c1.z; f7[q] = c1.w;
                f8v[q] = cs[(long)b * N + n];
                int a = actions[(long)b * N + n];
                a = min(max(a, 0), U - 1);
                ug[q] = unc[(long)b * U + a];
                acc[q] = 0.f;
            }

            const float* sBw = sB + w * 64;
            #pragma unroll 4
            for (int j = 0; j < 64; j++) {
                const float* pj = pack + j * 12;
                float4 wa = *(const float4*)(pj);
                float4 wb = *(const float4*)(pj + 4);
                float4 wc = *(const float4*)(pj + 8);
                float bse = sBw[j];
                #pragma unroll
                for (int q = 0; q < 4; q++) {
                    float zA = fmaf(f0[q], wa.x, bse);
                    zA = fmaf(f1[q], wa.y, zA);
                    zA = fmaf(f2[q], wa.z, zA);
                    zA = fmaf(f3[q], wa.w, zA);
                    float zB = f4[q] * wb.x;
                    zB = fmaf(f5[q], wb.y, zB);
                    zB = fmaf(f6[q], wb.z, zB);
                    zB = fmaf(f7[q], wb.w, zB);
                    zB = fmaf(f8v[q], wc.x, zB);
                    zB = fmaf(ug[q], wc.y, zB);
                    acc[q] = fmaf(fmaxf(zA + zB, 0.f), wc.z, acc[q]);
                }
            }

            #pragma unroll
            for (int q = 0; q < 4; q++)
                atomicAdd(&node_delta[(long)b * N + q * 64 + lane], acc[q]);
        }
    } else {
        // ================= EDGE: 1 row, quarter j, f16 =================
        int eb = blockIdx.x - 512;
        int b = eb >> 2, jq = eb & 3;
        float g = gate[b];
        if (g == 0.f) return;          // partial stays 0; k_fin2 handles

        float*  A4 = smem;                     // [64] float4 (f16x2 x4)
        float2* B2 = (float2*)(smem + 256);    // [64] float2
        float*  sC = smem + 768;               // [256][12]

        {
            const float4* g4 = (const float4*)(coords + (long)b * N * C);
            float4 c0 = g4[2 * t], c1 = g4[2 * t + 1];
            float4* d0 = (float4*)(sC + t * 12);
            d0[0] = c0; d0[1] = c1;
        }
        if (t < 64) {
            int j = jq * 64 + t;
            float w0 = We1[(long)(H + 0) * H + j];
            float w1 = We1[(long)(H + 1) * H + j];
            float w2 = We1[(long)(H + 2) * H + j];
            float w3 = We1[(long)(H + 3) * H + j];
            float w4 = We1[(long)(H + 4) * H + j];
            float w5 = We1[(long)(H + 5) * H + j];
            float w6 = We1[(long)(H + 6) * H + j];
            float w7 = We1[(long)(H + 7) * H + j];
            float w8 = We1[(long)(H + 8) * H + j];
            float w9 = We1[(long)(H + 9) * H + j];
            float we2 = We2[j];
            float bse = base_e[(long)b * H + j] + w9;   // emf==1 fold
            float4 av;
            av.x = bc_f(pkh(w0, w1)); av.y = bc_f(pkh(w2, w3));
            av.z = bc_f(pkh(w4, w5)); av.w = bc_f(pkh(w6, w7));
            ((float4*)A4)[t] = av;
            B2[t] = make_float2(bc_f(pkh(w8, we2)), bse);
        }
        __syncthreads();

        float p01[4], p23[4], p45[4], p67[4], pes[4], acc[4];
        #pragma unroll
        for (int q = 0; q < 4; q++) {
            long idx = (long)b * E + w * 256 + q * 64 + lane;
            int2 ev = ((const int2*)edges)[idx];
            int s0 = min(max(ev.x, 0), N - 1);
            int d0 = min(max(ev.y, 0), N - 1);
            const float4* cs4 = (const float4*)(sC + s0 * 12);
            const float4* cd4 = (const float4*)(sC + d0 * 12);
            float4 sa = cs4[0], sb = cs4[1];
            float4 da = cd4[0], db = cd4[1];
            p01[q] = bc_f(pkh(da.x - sa.x, da.y - sa.y));
            p23[q] = bc_f(pkh(da.z - sa.z, da.w - sa.w));
            p45[q] = bc_f(pkh(db.x - sb.x, db.y - sb.y));
            p67[q] = bc_f(pkh(db.z - sb.z, db.w - sb.w));
            pes[q] = bc_f(pkh(es[idx], 0.f));
            acc[q] = 0.f;
        }

        const float4* A4v = (const float4*)A4;
        #pragma unroll 4
        for (int j = 0; j < 64; j++) {
            float4 av = A4v[j];
            float2 bv = B2[j];
            h2 w01 = bc_h(av.x), w23 = bc_h(av.y);
            h2 w45 = bc_h(av.z), w67 = bc_h(av.w);
            h2 w8x = bc_h(bv.x);
            float we2f = (float)(w8x.y);
            float bse = bv.y;
            #pragma unroll
            for (int q = 0; q < 4; q++) {
                float z = FDOT2(bc_h(p01[q]), w01, bse);
                z = FDOT2(bc_h(p23[q]), w23, z);
                z = FDOT2(bc_h(p45[q]), w45, z);
                z = FDOT2(bc_h(p67[q]), w67, z);
                z = FDOT2(bc_h(pes[q]), w8x, z);
                acc[q] = fmaf(fmaxf(z, 0.f), we2f, acc[q]);
            }
        }

        #pragma unroll
        for (int q = 0; q < 4; q++)
            atomicAdd(&out2[(long)b * E + w * 256 + q * 64 + lane], acc[q]);
    }
}

// ---------------------------------------------------------------------------
// k_fin2: grid B, 512 threads = 8 waves (R19 verbatim). Wave 0 = node
// finalize (pure-shuffle); waves 4-7 = edge finalize. Concurrent halves.
// ---------------------------------------------------------------------------
__global__ __launch_bounds__(512) void k_fin2(
    const void* __restrict__ amask, const void* __restrict__ emask,
    const int* __restrict__ actions, const float* __restrict__ unc,
    const float* __restrict__ cs, const float* __restrict__ es,
    const float* __restrict__ bn2, const float* __restrict__ be2,
    const float* __restrict__ gate, const int* __restrict__ flagp,
    const float* __restrict__ node_delta,
    float* __restrict__ out0, float* __restrict__ out1,
    float* __restrict__ out2, float* __restrict__ out3,
    float* __restrict__ out4)
{
    __shared__ float sRisk;
    __shared__ float sS1[8], sCe[8], sVar[8];
    int t = threadIdx.x;
    int w = t >> 6, lane = t & 63;
    int b = blockIdx.x;
    int flag = *flagp;
    float g = gate[b];

    float re[4], emv[4];

    if (w == 0) {
        float b2v = bn2[0];
        float raw[4], amv[4], ug[4];
        #pragma unroll
        for (int q = 0; q < 4; q++) {
            long idx = (long)b * N + q * 64 + lane;
            amv[q] = mask_val(amask, idx, flag);
            float csv = cs[idx];
            int a = actions[idx];
            a = min(max(a, 0), U - 1);
            ug[q] = unc[(long)b * U + a];
            float nd = (node_delta[idx] + b2v) * amv[q];
            raw[q] = (csv + g * 0.1f * nd) * amv[q];
        }

        float s = 0.f, cn = 0.f, su = 0.f;
        #pragma unroll
        for (int q = 0; q < 4; q++) {
            s += raw[q]; cn += amv[q]; su += ug[q] * amv[q];
        }
        #pragma unroll
        for (int m = 1; m < 64; m <<= 1) {
            s  += __shfl_xor(s, m);
            cn += __shfl_xor(cn, m);
            su += __shfl_xor(su, m);
        }
        float denom = fmaxf(cn, 1.f);
        float mu = s / denom;

        float masked[4];
        #pragma unroll
        for (int q = 0; q < 4; q++) {
            float rs = (raw[q] - mu) * amv[q];
            out0[(long)b * N + q * 64 + lane] = rs;
            masked[q] = (amv[q] != 0.f) ? rs : -1e9f;
        }

        float v1 = masked[0]; int i1 = lane; float v2 = -1e9f;
        #pragma unroll
        for (int q = 1; q < 4; q++) {
            float mv = masked[q]; int mi = q * 64 + lane;
            if (mv > v1) { v2 = v1; v1 = mv; i1 = mi; }
            else v2 = fmaxf(v2, mv);
        }
        #pragma unroll
        for (int m = 1; m < 64; m <<= 1) {
            float ov1 = __shfl_xor(v1, m);
            int   oi1 = __shfl_xor(i1, m);
            float ov2 = __shfl_xor(v2, m);
            bool ow = (ov1 > v1) || (ov1 == v1 && oi1 < i1);
            float lv  = ow ? v1 : ov1;
            float wv2 = ow ? ov2 : v2;
            if (ow) { v1 = ov1; i1 = oi1; }
            v2 = fmaxf(lv, wv2);
        }

        if (lane == 0) {
            float rmargin = v1 - v2;
            out1[b] = rmargin;
            out3[b] = (float)i1;
            float sig = 1.f / (1.f + expf(rmargin));   // sigmoid(-margin)
            sRisk = sig + 0.1f * (su / denom);
            sS1[0] = 0.f; sCe[0] = 0.f;
        }
    } else if (w >= 4) {
        float be2v = be2[0];
        int eq = w - 4;
        float S1 = 0.f, ce = 0.f;
        #pragma unroll
        for (int q = 0; q < 4; q++) {
            long idx = (long)b * E + eq * 256 + q * 64 + lane;
            emv[q] = mask_val(emask, idx, flag);
            float delta = out2[idx] + be2v;
            float r = es[idx] + g * 0.1f * delta;
            re[q] = (emv[q] != 0.f) ? r : 0.f;
            out2[idx] = re[q];
            S1 += re[q]; ce += emv[q];
        }
        #pragma unroll
        for (int m = 1; m < 64; m <<= 1) {
            S1 += __shfl_xor(S1, m);
            ce += __shfl_xor(ce, m);
        }
        if (lane == 0) { sS1[w] = S1; sCe[w] = ce; }
    } else {
        if (lane == 0) { sS1[w] = 0.f; sCe[w] = 0.f; }
    }
    __syncthreads();

    float S1t = sS1[4] + sS1[5] + sS1[6] + sS1[7];
    float cet = sCe[4] + sCe[5] + sCe[6] + sCe[7];
    float mean = S1t / fmaxf(cet, 1.f);

    if (w >= 4) {
        float v = 0.f;
        #pragma unroll
        for (int q = 0; q < 4; q++) {
            float dd = re[q] - mean;
            v = fmaf(emv[q] * dd, dd, v);
        }
        #pragma unroll
        for (int m = 1; m < 64; m <<= 1) v += __shfl_xor(v, m);
        if (lane == 0) sVar[w] = v;
    } else {
        if (lane == 0) sVar[w] = 0.f;
    }
    __syncthreads();

    if (t == 0) {
        float vt = sVar[4] + sVar[5] + sVar[6] + sVar[7];
        float var = vt / fmaxf(cet, 1.f);
        float ev = (cet > 1.f) ? var : 0.f;
        float r = sRisk + 0.2f * ev;
        out4[b] = fminf(fmaxf(r, 0.f), 1.f);
    }
}

// ---------------------------------------------------------------------------
extern "C" void kernel_launch(void* const* d_in, const int* in_sizes, int n_in,
                              void* d_out, int out_size, void* d_ws, size_t ws_size,
                              hipStream_t stream) {
    const float* feat   = (const float*)d_in[0];
    const float* cs     = (const float*)d_in[1];
    const float* marg   = (const float*)d_in[2];
    const float* brisk  = (const float*)d_in[3];
    const float* es     = (const float*)d_in[4];
    const float* coords = (const float*)d_in[5];
    const float* unc    = (const float*)d_in[6];
    const float* Wc1    = (const float*)d_in[7];
    const float* bc1    = (const float*)d_in[8];
    const float* Wc2    = (const float*)d_in[9];
    const float* bc2    = (const float*)d_in[10];
    const float* Wn1    = (const float*)d_in[11];
    const float* bn1    = (const float*)d_in[12];
    const float* Wn2    = (const float*)d_in[13];
    const float* bn2    = (const float*)d_in[14];
    const float* We1    = (const float*)d_in[15];
    const float* be1    = (const float*)d_in[16];
    const float* We2    = (const float*)d_in[17];
    const float* be2    = (const float*)d_in[18];
    const float* Wg     = (const float*)d_in[19];
    const float* bg     = (const float*)d_in[20];
    const void*  amask  = d_in[21];
    const void*  emask  = d_in[22];
    const int*   actions= (const int*)d_in[23];
    const int*   edges  = (const int*)d_in[24];

    float* out0 = (float*)d_out;           // refined_scores (B,N)
    float* out1 = out0 + (long)B * N;      // refined_margin (B,)
    float* out2 = out1 + B;                // refined_edge (B,E)
    float* out3 = out2 + (long)B * E;      // top_idx (B,) as float
    float* out4 = out3 + B;                // refined_risk (B,)
    float* out5 = out4 + B;                // refine_gate (B,)

    float* base_n     = (float*)d_ws;                  // B*H
    float* base_e     = base_n + (long)B * H;          // B*H
    float* node_delta = base_e + (long)B * H;          // B*N
    float* A_ws       = node_delta + (long)B * N;      // B*H
    float* h_ws       = A_ws + (long)B * H;            // B*H
    float* gate_part  = h_ws + (long)B * H;            // 4*B
    int*   flag       = (int*)(gate_part + 4 * B);

    k_h1<<<512, 256, 0, stream>>>(feat, Wc1, bc1,
                                  (const unsigned int*)amask,
                                  A_ws, flag, node_delta, out2, gate_part);
    k_h2<<<512, 256, 0, stream>>>(A_ws, Wc2, bc2, Wg, h_ws, gate_part);
    k_h3<<<1024, 256, 0, stream>>>(h_ws, Wn1, bn1, We1, be1, bg,
                                   marg, brisk, gate_part,
                                   base_n, base_e, out5);
    k_ne<<<512 + 4 * B, 256, 0, stream>>>(cs, coords, unc, actions,
                                          Wn1, Wn2, base_n,
                                          es, edges,
                                          We1, We2, base_e,
                                          out5, node_delta, out2);
    k_fin2<<<B, 512, 0, stream>>>(amask, emask, actions, unc, cs, es,
                                  bn2, be2, out5, flag, node_delta,
                                  out0, out1, out2, out3, out4);
}

// Round 21
// 69.220 us; speedup vs baseline: 1.0594x; 1.0594x over previous
//
#include <hip/hip_runtime.h>
#include <math.h>

#define B 512
#define N 256
#define E 1024
#define D 256
#define H 256
#define C 8
#define U 64

typedef __fp16 h2 __attribute__((ext_vector_type(2)));
union UF { float f; h2 h; unsigned u; };

__device__ __forceinline__ float bc_f(h2 h) { UF u; u.h = h; return u.f; }
__device__ __forceinline__ h2 bc_h(float f) { UF u; u.f = f; return u.h; }

#if __has_builtin(__builtin_amdgcn_cvt_pkrtz)
__device__ __forceinline__ h2 pkh(float a, float b) { return __builtin_amdgcn_cvt_pkrtz(a, b); }
#else
__device__ __forceinline__ h2 pkh(float a, float b) { h2 r; r.x = (__fp16)a; r.y = (__fp16)b; return r; }
#endif

#if __has_builtin(__builtin_amdgcn_fdot2)
__device__ __forceinline__ float FDOT2(h2 a, h2 b, float c) { return __builtin_amdgcn_fdot2(a, b, c, false); }
#else
__device__ __forceinline__ float FDOT2(h2 a, h2 b, float c) {
    return fmaf((float)a.x, (float)b.x, fmaf((float)a.y, (float)b.y, c));
}
#endif

// ---------------------------------------------------------------------------
__device__ __forceinline__ float mask_val(const void* m, long i, int flag) {
    if (flag == 1) return ((const unsigned char*)m)[i] ? 1.f : 0.f;
    if (flag == 2) return (((const float*)m)[i] != 0.f) ? 1.f : 0.f;
    return ((const int*)m)[i] ? 1.f : 0.f;
}

// ---------------------------------------------------------------------------
// k_h: trunk, 2 rows/block, 512 threads, grid=256 (R14 proven form). Zeroes
// the partial accumulators and sniffs the mask dtype (block 0).
// ---------------------------------------------------------------------------
__global__ __launch_bounds__(512) void k_h(
    const float* __restrict__ feat,
    const float* __restrict__ Wc1, const float* __restrict__ bc1,
    const float* __restrict__ Wc2, const float* __restrict__ bc2,
    const float* __restrict__ Wn1, const float* __restrict__ bn1,
    const float* __restrict__ We1, const float* __restrict__ be1,
    const float* __restrict__ Wg,  const float* __restrict__ bg,
    const float* __restrict__ margin, const float* __restrict__ brisk,
    const unsigned int* __restrict__ amask_words,
    float* __restrict__ base_n, float* __restrict__ base_e,
    float* __restrict__ out_gate, int* __restrict__ flag,
    float* __restrict__ node_delta, float* __restrict__ out2)
{
    __shared__ __align__(16) float sF[2][256];
    __shared__ __align__(16) float sH[2][256];
    __shared__ float red[512];
    __shared__ int cls0, cls1;

    int t = threadIdx.x;
    int w = t >> 8;        // 0/1: row in P1/P2, matrix in P3
    int c = t & 255;
    int b0 = blockIdx.x * 2;
    int b = b0 + w;

    // zero partial accumulators: 256 blocks x 512 thr
    {
        int idx = blockIdx.x * 512 + t;
        node_delta[idx] = 0.f;
        ((float4*)out2)[idx] = make_float4(0.f, 0.f, 0.f, 0.f);
    }

    if (blockIdx.x == 0) {
        if (t == 0) { cls0 = 0; cls1 = 0; }
        __syncthreads();
        if (t < 256) {
            unsigned int wd = amask_words[t];
            if (wd != 0u && wd != 1u) {
                if (wd == 0x3f800000u) atomicOr(&cls1, 1);
                else                   atomicOr(&cls0, 1);
            }
        }
        __syncthreads();
        if (t == 0) *flag = cls0 ? 1 : (cls1 ? 2 : 0);
    }

    sF[w][c] = feat[(long)b * D + c];
    __syncthreads();

    // ---- P1 ----
    {
        float acc[4] = {bc1[c], 0.f, 0.f, 0.f};
        const float* Wp = Wc1 + c;
        for (int d0 = 0; d0 < D; d0 += 16) {
            float wv[16];
            #pragma unroll
            for (int k = 0; k < 16; k++) wv[k] = Wp[(long)(d0 + k) * H];
            #pragma unroll
            for (int k = 0; k < 16; k++)
                acc[k & 3] = fmaf(sF[w][d0 + k], wv[k], acc[k & 3]);
        }
        sH[w][c] = fmaxf((acc[0] + acc[1]) + (acc[2] + acc[3]), 0.f);
    }
    __syncthreads();

    // ---- P2 ----
    {
        float acc[4] = {bc2[c], 0.f, 0.f, 0.f};
        const float* Wp = Wc2 + c;
        for (int d0 = 0; d0 < H; d0 += 16) {
            float wv[16];
            #pragma unroll
            for (int k = 0; k < 16; k++) wv[k] = Wp[(long)(d0 + k) * H];
            #pragma unroll
            for (int k = 0; k < 16; k++)
                acc[k & 3] = fmaf(sH[w][d0 + k], wv[k], acc[k & 3]);
        }
        float a = fmaxf((acc[0] + acc[1]) + (acc[2] + acc[3]), 0.f);
        __syncthreads();
        sF[w][c] = a;                 // sF now holds h for both rows
    }
    __syncthreads();

    // ---- gate per row ----
    red[t] = sF[w][c] * Wg[c];
    __syncthreads();
    for (int s = 128; s > 0; s >>= 1) {
        if (c < s) red[t] += red[t + s];
        __syncthreads();
    }
    if (c == 0) {
        float lg = 1.f / (1.f + expf(-(red[t] + bg[0])));
        out_gate[b] = ((margin[b] < 0.2f) || (brisk[b] > 0.6f) || (lg > 0.5f)) ? 1.f : 0.f;
    }

    // ---- P3: base_n / base_e (thread-half = matrix, both rows) ----
    {
        const float* W3  = w ? (We1 + c) : (Wn1 + c);
        float bias       = w ? be1[c]    : bn1[c];
        float* dst       = w ? base_e    : base_n;
        float aA[2] = {bias, 0.f};
        float aB[2] = {bias, 0.f};
        for (int d0 = 0; d0 < H; d0 += 16) {
            float wv[16];
            #pragma unroll
            for (int k = 0; k < 16; k++) wv[k] = W3[(long)(d0 + k) * H];
            #pragma unroll
            for (int k = 0; k < 16; k++) {
                aA[k & 1] = fmaf(sF[0][d0 + k], wv[k], aA[k & 1]);
                aB[k & 1] = fmaf(sF[1][d0 + k], wv[k], aB[k & 1]);
            }
        }
        dst[(long)b0 * H + c]       = aA[0] + aA[1];
        dst[(long)(b0 + 1) * H + c] = aB[0] + aB[1];
    }
}

// ---------------------------------------------------------------------------
// k_ne: j-split x4 (64 j per block) — grid 2560 (best measured structure).
// Blocks [0,512): NODE — rg=bid>>2 (4 rows, wave=row), jq=bid&3, fp32 q=4.
// Blocks [512,2560): EDGE — b=(bid-512)>>2, jq=&3, q=4 f16 fdot2.
// atomicAdd partials into node_delta / out2 (zeroed by k_h).
// ---------------------------------------------------------------------------
__global__ __launch_bounds__(256, 2) void k_ne(
    const float* __restrict__ cs, const float* __restrict__ coords,
    const float* __restrict__ unc, const int* __restrict__ actions,
    const float* __restrict__ Wn1, const float* __restrict__ Wn2,
    const float* __restrict__ base_n,
    const float* __restrict__ es, const int* __restrict__ edges,
    const float* __restrict__ We1, const float* __restrict__ We2,
    const float* __restrict__ base_e,
    const float* __restrict__ gate,
    float* __restrict__ node_delta, float* __restrict__ out2)
{
    __shared__ __align__(16) float smem[3840];   // 15 KB
    int t = threadIdx.x;
    int w = t >> 6, lane = t & 63;

    if (blockIdx.x < 512) {
        // ================= NODE: 4 rows (wave=row), quarter j =============
        int rg = blockIdx.x >> 2;
        int jq = blockIdx.x & 3;
        int b0 = rg * 4;
        float* pack = smem;            // [64][12]
        float* sB   = smem + 768;      // [4][64]

        {
            int i = t;
            #pragma unroll
            for (int s = 0; s < 3; s++, i += 256) {
                int j = i / 12, k = i - j * 12;
                int jj = jq * 64 + j;
                float v;
                if (k < 10)       v = Wn1[(long)(H + k) * H + jj];
                else if (k == 10) v = Wn2[jj];
                else              v = 0.f;
                pack[i] = v;
            }
            int r = t >> 6, j = t & 63;
            sB[r * 64 + j] = base_n[(long)(b0 + r) * H + jq * 64 + j];
        }
        __syncthreads();

        int b = b0 + w;
        float g = gate[b];
        if (g != 0.f) {
            float f8v[4], ug[4], acc[4];
            float f0[4], f1[4], f2[4], f3[4], f4[4], f5[4], f6[4], f7[4];
            #pragma unroll
            for (int q = 0; q < 4; q++) {
                int n = q * 64 + lane;
                const float4* cp = (const float4*)(coords + ((long)b * N + n) * C);
                float4 c0 = cp[0], c1 = cp[1];
                f0[q] = c0.x; f1[q] = c0.y; f2[q] = c0.z; f3[q] = c0.w;
                f4[q] = c1.x; f5[q] = c1.y; f6[q] = c1.z; f7[q] = c1.w;
                f8v[q] = cs[(long)b * N + n];
                int a = actions[(long)b * N + n];
                a = min(max(a, 0), U - 1);
                ug[q] = unc[(long)b * U + a];
                acc[q] = 0.f;
            }

            const float* sBw = sB + w * 64;
            #pragma unroll 4
            for (int j = 0; j < 64; j++) {
                const float* pj = pack + j * 12;
                float4 wa = *(const float4*)(pj);
                float4 wb = *(const float4*)(pj + 4);
                float4 wc = *(const float4*)(pj + 8);
                float bse = sBw[j];
                #pragma unroll
                for (int q = 0; q < 4; q++) {
                    float zA = fmaf(f0[q], wa.x, bse);
                    zA = fmaf(f1[q], wa.y, zA);
                    zA = fmaf(f2[q], wa.z, zA);
                    zA = fmaf(f3[q], wa.w, zA);
                    float zB = f4[q] * wb.x;
                    zB = fmaf(f5[q], wb.y, zB);
                    zB = fmaf(f6[q], wb.z, zB);
                    zB = fmaf(f7[q], wb.w, zB);
                    zB = fmaf(f8v[q], wc.x, zB);
                    zB = fmaf(ug[q], wc.y, zB);
                    acc[q] = fmaf(fmaxf(zA + zB, 0.f), wc.z, acc[q]);
                }
            }

            #pragma unroll
            for (int q = 0; q < 4; q++)
                atomicAdd(&node_delta[(long)b * N + q * 64 + lane], acc[q]);
        }
    } else {
        // ================= EDGE: 1 row, quarter j, f16 =================
        int eb = blockIdx.x - 512;
        int b = eb >> 2, jq = eb & 3;
        float g = gate[b];
        if (g == 0.f) return;          // partial stays 0; k_fin2 handles

        float*  A4 = smem;                     // [64] float4 (f16x2 x4)
        float2* B2 = (float2*)(smem + 256);    // [64] float2
        float*  sC = smem + 768;               // [256][12]

        {
            const float4* g4 = (const float4*)(coords + (long)b * N * C);
            float4 c0 = g4[2 * t], c1 = g4[2 * t + 1];
            float4* d0 = (float4*)(sC + t * 12);
            d0[0] = c0; d0[1] = c1;
        }
        if (t < 64) {
            int j = jq * 64 + t;
            float w0 = We1[(long)(H + 0) * H + j];
            float w1 = We1[(long)(H + 1) * H + j];
            float w2 = We1[(long)(H + 2) * H + j];
            float w3 = We1[(long)(H + 3) * H + j];
            float w4 = We1[(long)(H + 4) * H + j];
            float w5 = We1[(long)(H + 5) * H + j];
            float w6 = We1[(long)(H + 6) * H + j];
            float w7 = We1[(long)(H + 7) * H + j];
            float w8 = We1[(long)(H + 8) * H + j];
            float w9 = We1[(long)(H + 9) * H + j];
            float we2 = We2[j];
            float bse = base_e[(long)b * H + j] + w9;   // emf==1 fold
            float4 av;
            av.x = bc_f(pkh(w0, w1)); av.y = bc_f(pkh(w2, w3));
            av.z = bc_f(pkh(w4, w5)); av.w = bc_f(pkh(w6, w7));
            ((float4*)A4)[t] = av;
            B2[t] = make_float2(bc_f(pkh(w8, we2)), bse);
        }
        __syncthreads();

        float p01[4], p23[4], p45[4], p67[4], pes[4], acc[4];
        #pragma unroll
        for (int q = 0; q < 4; q++) {
            long idx = (long)b * E + w * 256 + q * 64 + lane;
            int2 ev = ((const int2*)edges)[idx];
            int s0 = min(max(ev.x, 0), N - 1);
            int d0 = min(max(ev.y, 0), N - 1);
            const float4* cs4 = (const float4*)(sC + s0 * 12);
            const float4* cd4 = (const float4*)(sC + d0 * 12);
            float4 sa = cs4[0], sb = cs4[1];
            float4 da = cd4[0], db = cd4[1];
            p01[q] = bc_f(pkh(da.x - sa.x, da.y - sa.y));
            p23[q] = bc_f(pkh(da.z - sa.z, da.w - sa.w));
            p45[q] = bc_f(pkh(db.x - sb.x, db.y - sb.y));
            p67[q] = bc_f(pkh(db.z - sb.z, db.w - sb.w));
            pes[q] = bc_f(pkh(es[idx], 0.f));
            acc[q] = 0.f;
        }

        const float4* A4v = (const float4*)A4;
        #pragma unroll 4
        for (int j = 0; j < 64; j++) {
            float4 av = A4v[j];
            float2 bv = B2[j];
            h2 w01 = bc_h(av.x), w23 = bc_h(av.y);
            h2 w45 = bc_h(av.z), w67 = bc_h(av.w);
            h2 w8x = bc_h(bv.x);
            float we2f = (float)(w8x.y);
            float bse = bv.y;
            #pragma unroll
            for (int q = 0; q < 4; q++) {
                float z = FDOT2(bc_h(p01[q]), w01, bse);
                z = FDOT2(bc_h(p23[q]), w23, z);
                z = FDOT2(bc_h(p45[q]), w45, z);
                z = FDOT2(bc_h(p67[q]), w67, z);
                z = FDOT2(bc_h(pes[q]), w8x, z);
                acc[q] = fmaf(fmaxf(z, 0.f), we2f, acc[q]);
            }
        }

        #pragma unroll
        for (int q = 0; q < 4; q++)
            atomicAdd(&out2[(long)b * E + w * 256 + q * 64 + lane], acc[q]);
    }
}

// ---------------------------------------------------------------------------
// k_fin2: grid B, 512 threads = 8 waves. Wave 0 = node finalize (pure-shuffle
// centering, top-2+idx, margin, riskbase in LDS); waves 4-7 = edge finalize
// (256 edges each, mean/var). Halves run CONCURRENTLY; 2 uniform barriers.
// ---------------------------------------------------------------------------
__global__ __launch_bounds__(512) void k_fin2(
    const void* __restrict__ amask, const void* __restrict__ emask,
    const int* __restrict__ actions, const float* __restrict__ unc,
    const float* __restrict__ cs, const float* __restrict__ es,
    const float* __restrict__ bn2, const float* __restrict__ be2,
    const float* __restrict__ gate, const int* __restrict__ flagp,
    const float* __restrict__ node_delta,
    float* __restrict__ out0, float* __restrict__ out1,
    float* __restrict__ out2, float* __restrict__ out3,
    float* __restrict__ out4)
{
    __shared__ float sRisk;
    __shared__ float sS1[8], sCe[8], sVar[8];
    int t = threadIdx.x;
    int w = t >> 6, lane = t & 63;
    int b = blockIdx.x;
    int flag = *flagp;
    float g = gate[b];

    float re[4], emv[4];

    if (w == 0) {
        float b2v = bn2[0];
        float raw[4], amv[4], ug[4];
        #pragma unroll
        for (int q = 0; q < 4; q++) {
            long idx = (long)b * N + q * 64 + lane;
            amv[q] = mask_val(amask, idx, flag);
            float csv = cs[idx];
            int a = actions[idx];
            a = min(max(a, 0), U - 1);
            ug[q] = unc[(long)b * U + a];
            float nd = (node_delta[idx] + b2v) * amv[q];
            raw[q] = (csv + g * 0.1f * nd) * amv[q];
        }

        float s = 0.f, cn = 0.f, su = 0.f;
        #pragma unroll
        for (int q = 0; q < 4; q++) {
            s += raw[q]; cn += amv[q]; su += ug[q] * amv[q];
        }
        #pragma unroll
        for (int m = 1; m < 64; m <<= 1) {
            s  += __shfl_xor(s, m);
            cn += __shfl_xor(cn, m);
            su += __shfl_xor(su, m);
        }
        float denom = fmaxf(cn, 1.f);
        float mu = s / denom;

        float masked[4];
        #pragma unroll
        for (int q = 0; q < 4; q++) {
            float rs = (raw[q] - mu) * amv[q];
            out0[(long)b * N + q * 64 + lane] = rs;
            masked[q] = (amv[q] != 0.f) ? rs : -1e9f;
        }

        float v1 = masked[0]; int i1 = lane; float v2 = -1e9f;
        #pragma unroll
        for (int q = 1; q < 4; q++) {
            float mv = masked[q]; int mi = q * 64 + lane;
            if (mv > v1) { v2 = v1; v1 = mv; i1 = mi; }
            else v2 = fmaxf(v2, mv);
        }
        #pragma unroll
        for (int m = 1; m < 64; m <<= 1) {
            float ov1 = __shfl_xor(v1, m);
            int   oi1 = __shfl_xor(i1, m);
            float ov2 = __shfl_xor(v2, m);
            bool ow = (ov1 > v1) || (ov1 == v1 && oi1 < i1);
            float lv  = ow ? v1 : ov1;
            float wv2 = ow ? ov2 : v2;
            if (ow) { v1 = ov1; i1 = oi1; }
            v2 = fmaxf(lv, wv2);
        }

        if (lane == 0) {
            float rmargin = v1 - v2;
            out1[b] = rmargin;
            out3[b] = (float)i1;
            float sig = 1.f / (1.f + expf(rmargin));   // sigmoid(-margin)
            sRisk = sig + 0.1f * (su / denom);
            sS1[0] = 0.f; sCe[0] = 0.f;
        }
    } else if (w >= 4) {
        float be2v = be2[0];
        int eq = w - 4;
        float S1 = 0.f, ce = 0.f;
        #pragma unroll
        for (int q = 0; q < 4; q++) {
            long idx = (long)b * E + eq * 256 + q * 64 + lane;
            emv[q] = mask_val(emask, idx, flag);
            float delta = out2[idx] + be2v;
            float r = es[idx] + g * 0.1f * delta;
            re[q] = (emv[q] != 0.f) ? r : 0.f;
            out2[idx] = re[q];
            S1 += re[q]; ce += emv[q];
        }
        #pragma unroll
        for (int m = 1; m < 64; m <<= 1) {
            S1 += __shfl_xor(S1, m);
            ce += __shfl_xor(ce, m);
        }
        if (lane == 0) { sS1[w] = S1; sCe[w] = ce; }
    } else {
        if (lane == 0) { sS1[w] = 0.f; sCe[w] = 0.f; }
    }
    __syncthreads();

    float S1t = sS1[4] + sS1[5] + sS1[6] + sS1[7];
    float cet = sCe[4] + sCe[5] + sCe[6] + sCe[7];
    float mean = S1t / fmaxf(cet, 1.f);

    if (w >= 4) {
        float v = 0.f;
        #pragma unroll
        for (int q = 0; q < 4; q++) {
            float dd = re[q] - mean;
            v = fmaf(emv[q] * dd, dd, v);
        }
        #pragma unroll
        for (int m = 1; m < 64; m <<= 1) v += __shfl_xor(v, m);
        if (lane == 0) sVar[w] = v;
    } else {
        if (lane == 0) sVar[w] = 0.f;
    }
    __syncthreads();

    if (t == 0) {
        float vt = sVar[4] + sVar[5] + sVar[6] + sVar[7];
        float var = vt / fmaxf(cet, 1.f);
        float ev = (cet > 1.f) ? var : 0.f;
        float r = sRisk + 0.2f * ev;
        out4[b] = fminf(fmaxf(r, 0.f), 1.f);
    }
}

// ---------------------------------------------------------------------------
extern "C" void kernel_launch(void* const* d_in, const int* in_sizes, int n_in,
                              void* d_out, int out_size, void* d_ws, size_t ws_size,
                              hipStream_t stream) {
    const float* feat   = (const float*)d_in[0];
    const float* cs     = (const float*)d_in[1];
    const float* marg   = (const float*)d_in[2];
    const float* brisk  = (const float*)d_in[3];
    const float* es     = (const float*)d_in[4];
    const float* coords = (const float*)d_in[5];
    const float* unc    = (const float*)d_in[6];
    const float* Wc1    = (const float*)d_in[7];
    const float* bc1    = (const float*)d_in[8];
    const float* Wc2    = (const float*)d_in[9];
    const float* bc2    = (const float*)d_in[10];
    const float* Wn1    = (const float*)d_in[11];
    const float* bn1    = (const float*)d_in[12];
    const float* Wn2    = (const float*)d_in[13];
    const float* bn2    = (const float*)d_in[14];
    const float* We1    = (const float*)d_in[15];
    const float* be1    = (const float*)d_in[16];
    const float* We2    = (const float*)d_in[17];
    const float* be2    = (const float*)d_in[18];
    const float* Wg     = (const float*)d_in[19];
    const float* bg     = (const float*)d_in[20];
    const void*  amask  = d_in[21];
    const void*  emask  = d_in[22];
    const int*   actions= (const int*)d_in[23];
    const int*   edges  = (const int*)d_in[24];

    float* out0 = (float*)d_out;           // refined_scores (B,N)
    float* out1 = out0 + (long)B * N;      // refined_margin (B,)
    float* out2 = out1 + B;                // refined_edge (B,E)
    float* out3 = out2 + (long)B * E;      // top_idx (B,) as float
    float* out4 = out3 + B;                // refined_risk (B,)
    float* out5 = out4 + B;                // refine_gate (B,)

    float* base_n     = (float*)d_ws;                  // B*H
    float* base_e     = base_n + (long)B * H;          // B*H
    float* node_delta = base_e + (long)B * H;          // B*N
    int*   flag       = (int*)(node_delta + (long)B * N);

    k_h<<<B / 2, 512, 0, stream>>>(feat, Wc1, bc1, Wc2, bc2, Wn1, bn1, We1, be1,
                                   Wg, bg, marg, brisk,
                                   (const unsigned int*)amask,
                                   base_n, base_e, out5, flag,
                                   node_delta, out2);
    k_ne<<<512 + 4 * B, 256, 0, stream>>>(cs, coords, unc, actions,
                                          Wn1, Wn2, base_n,
                                          es, edges,
                                          We1, We2, base_e,
                                          out5, node_delta, out2);
    k_fin2<<<B, 512, 0, stream>>>(amask, emask, actions, unc, cs, es,
                                  bn2, be2, out5, flag, node_delta,
                                  out0, out1, out2, out3, out4);
}